// Round 3
// baseline (826.755 us; speedup 1.0000x reference)
//
#include <hip/hip_runtime.h>

#define TOK  16384
#define NEXP 8
#define DIM  1024
#define DDIM 4096
#define KCAP 2048

typedef float  floatx4 __attribute__((ext_vector_type(4)));
typedef short  shortx8 __attribute__((ext_vector_type(8)));

static __device__ __forceinline__ unsigned short f2bf(float x) {
  unsigned u = __float_as_uint(x);
  return (unsigned short)((u + 0x7fffu + ((u >> 16) & 1u)) >> 16);
}

// ---------------- fp32 -> bf16 weight convert ----------------
__global__ __launch_bounds__(256) void cvt_kernel(const float* __restrict__ src,
                                                  unsigned short* __restrict__ dst, int n4) {
  int i = blockIdx.x * 256 + threadIdx.x;
  if (i < n4) {
    float4 v = ((const float4*)src)[i];
    ushort4 o = make_ushort4(f2bf(v.x), f2bf(v.y), f2bf(v.z), f2bf(v.w));
    ((ushort4*)dst)[i] = o;
  }
}

// ---------------- gating: logits + softmax ----------------
__global__ __launch_bounds__(256) void gate_kernel(const float* __restrict__ x,
                                                   const float* __restrict__ gw,
                                                   float* __restrict__ scores) {
  __shared__ float gws[NEXP * DIM];
  int tid = threadIdx.x;
  for (int i = tid; i < NEXP * DIM / 4; i += 256)
    ((float4*)gws)[i] = ((const float4*)gw)[i];
  __syncthreads();
  int wave = tid >> 6, lane = tid & 63;
  int t = blockIdx.x * 4 + wave;
  const float4* xr = (const float4*)(x + (size_t)t * DIM);
  float4 xv[4];
#pragma unroll
  for (int j = 0; j < 4; ++j) xv[j] = xr[j * 64 + lane];
  float acc[NEXP];
#pragma unroll
  for (int e = 0; e < NEXP; ++e) acc[e] = 0.f;
#pragma unroll
  for (int e = 0; e < NEXP; ++e) {
    const float4* g4 = (const float4*)(gws + e * DIM);
#pragma unroll
    for (int j = 0; j < 4; ++j) {
      float4 g = g4[j * 64 + lane];
      acc[e] += xv[j].x * g.x + xv[j].y * g.y + xv[j].z * g.z + xv[j].w * g.w;
    }
  }
#pragma unroll
  for (int off = 32; off > 0; off >>= 1) {
#pragma unroll
    for (int e = 0; e < NEXP; ++e) acc[e] += __shfl_down(acc[e], off);
  }
  if (lane == 0) {
    float mx = acc[0];
#pragma unroll
    for (int e = 1; e < NEXP; ++e) mx = fmaxf(mx, acc[e]);
    float ex[NEXP], sum = 0.f;
#pragma unroll
    for (int e = 0; e < NEXP; ++e) { ex[e] = expf(acc[e] - mx); sum += ex[e]; }
    float inv = 1.f / sum;
#pragma unroll
    for (int e = 0; e < NEXP; ++e) scores[(size_t)e * TOK + t] = ex[e] * inv;
  }
}

// ---------------- per-expert exact top-k via 3-level histogram radix select ----------
// Levels: bits [31:21] (2048 bins), [20:10] (2048), [9:0] (1024). Positive floats
// order as uint bits. Wave-0 cooperative suffix-scan walk finds, per level, the
// highest bin where count(v >= bin-prefix) >= KCAP; cnt_above tracks count(v > prefix).
// After level 3: T = exact k-th-largest bits, n_gt = count(v > T). Selection pass
// (lowest-index tie-break) identical to the verified radix-search version.
#define TKT 1024
#define TKW (TKT / 64)

__device__ __forceinline__ void walk_suffix(const int* hist, int nbins, int cnt_in,
                                            int tid, int* shOut) {
  if (tid < 64) {
    int lane = tid;
    int cum = 0;
    for (int g = nbins / 64 - 1; g >= 0; --g) {
      int c = hist[g * 64 + lane];
      int s = c;
#pragma unroll
      for (int off = 1; off < 64; off <<= 1) {
        int o = __shfl_down(s, off);
        if (lane + off < 64) s += o;
      }
      int gs = __shfl(s, 0);
      if (cnt_in + cum + gs >= KCAP) {
        unsigned long long m = __ballot(cnt_in + cum + s >= KCAP);
        int l = 63 - __clzll(m);
        int sAt = __shfl(s, l), cAt = __shfl(c, l);
        if (lane == 0) { shOut[0] = g * 64 + l; shOut[1] = cnt_in + cum + sAt - cAt; }
        break;
      }
      cum += gs;
    }
  }
}

__global__ __launch_bounds__(TKT) void topk_kernel(const float* __restrict__ scores,
                                                   int* __restrict__ sel,
                                                   float* __restrict__ selw) {
  int e = blockIdx.x;
  const float* s = scores + (size_t)e * TOK;
  int tid = threadIdx.x, lane = tid & 63, wave = tid >> 6;
  __shared__ int hist[2048];
  __shared__ int shBin[2];
  __shared__ int wsum[TKW];

  // level 1: bits [31:21]
  for (int i = tid; i < 2048; i += TKT) hist[i] = 0;
  __syncthreads();
  for (int i = tid; i < TOK; i += TKT)
    atomicAdd(&hist[__float_as_uint(s[i]) >> 21], 1);
  __syncthreads();
  walk_suffix(hist, 2048, 0, tid, shBin);
  __syncthreads();
  unsigned bin1 = (unsigned)shBin[0];
  int cab = shBin[1];
  __syncthreads();

  // level 2: bits [20:10] within bin1
  for (int i = tid; i < 2048; i += TKT) hist[i] = 0;
  __syncthreads();
  for (int i = tid; i < TOK; i += TKT) {
    unsigned v = __float_as_uint(s[i]);
    if ((v >> 21) == bin1) atomicAdd(&hist[(v >> 10) & 0x7FFu], 1);
  }
  __syncthreads();
  walk_suffix(hist, 2048, cab, tid, shBin);
  __syncthreads();
  unsigned pre21 = (bin1 << 11) | (unsigned)shBin[0];
  cab = shBin[1];
  __syncthreads();

  // level 3: bits [9:0] within pre21
  for (int i = tid; i < 1024; i += TKT) hist[i] = 0;
  __syncthreads();
  for (int i = tid; i < TOK; i += TKT) {
    unsigned v = __float_as_uint(s[i]);
    if ((v >> 10) == pre21) atomicAdd(&hist[v & 0x3FFu], 1);
  }
  __syncthreads();
  walk_suffix(hist, 1024, cab, tid, shBin);
  __syncthreads();
  unsigned T = (pre21 << 10) | (unsigned)shBin[0];
  int n_gt = shBin[1];
  int need = KCAP - n_gt;

  __shared__ int pos;
  __shared__ int tiebase;
  if (tid == 0) { pos = 0; tiebase = 0; }
  __syncthreads();
  for (int chunk = 0; chunk < TOK; chunk += TKT) {
    int i = chunk + tid;
    unsigned v = __float_as_uint(s[i]);
    if (v > T) {
      int p = atomicAdd(&pos, 1);
      sel[e * KCAP + p]  = i;
      selw[e * KCAP + p] = __uint_as_float(v);
    }
    bool tie = (v == T);
    unsigned long long m = __ballot(tie);
    if (lane == 0) wsum[wave] = __popcll(m);
    __syncthreads();
    int base = tiebase;
    for (int w = 0; w < wave; ++w) base += wsum[w];
    int rank = base + __popcll(m & ((1ull << lane) - 1ull));
    if (tie && rank < need) {
      sel[e * KCAP + n_gt + rank]  = i;
      selw[e * KCAP + n_gt + rank] = __uint_as_float(T);
    }
    __syncthreads();
    if (tid == 0) {
      int tb = 0;
#pragma unroll
      for (int w = 0; w < TKW; ++w) tb += wsum[w];
      tiebase += tb;
    }
    __syncthreads();
  }
}

// ---------------- gather selected tokens + layernorm -> bf16 Y ----------------
__global__ __launch_bounds__(256) void gather_ln_kernel(const float* __restrict__ x,
                                                        const int* __restrict__ sel,
                                                        const float* __restrict__ lnw,
                                                        const float* __restrict__ lnb,
                                                        unsigned short* __restrict__ Y) {
  int e = blockIdx.y, i = blockIdx.x;
  int tid = threadIdx.x, lane = tid & 63, wave = tid >> 6;
  int t = sel[e * KCAP + i];
  const float4* xr = (const float4*)(x + (size_t)t * DIM);
  float4 v = xr[tid];
  float s  = v.x + v.y + v.z + v.w;
  float sq = v.x * v.x + v.y * v.y + v.z * v.z + v.w * v.w;
#pragma unroll
  for (int off = 32; off > 0; off >>= 1) { s += __shfl_down(s, off); sq += __shfl_down(sq, off); }
  __shared__ float red[8];
  if (lane == 0) { red[wave] = s; red[4 + wave] = sq; }
  __syncthreads();
  s  = red[0] + red[1] + red[2] + red[3];
  sq = red[4] + red[5] + red[6] + red[7];
  float mu  = s * (1.f / DIM);
  float var = sq * (1.f / DIM) - mu * mu;
  float rs  = rsqrtf(var + 1e-5f);
  float4 w = ((const float4*)lnw)[tid];
  float4 b = ((const float4*)lnb)[tid];
  ushort4 o = make_ushort4(f2bf((v.x - mu) * rs * w.x + b.x),
                           f2bf((v.y - mu) * rs * w.y + b.y),
                           f2bf((v.z - mu) * rs * w.z + b.z),
                           f2bf((v.w - mu) * rs * w.w + b.w));
  ((ushort4*)(Y + ((size_t)e * KCAP + i) * DIM))[tid] = o;
}

// ---------------- bf16 MFMA GEMM: 256x256 tile, BK=64, 8-wave 8-phase pipeline ----------
// Schedule invariant (R1-verified): ALL four halves of tile t+1 complete before t+1.P0,
// because each wave reads its OWN half (m_w for A, hb for B) starting at P0.
// Max-slack staging within that invariant:
//   t.P0: stage Ah1,Bh1(t+1) -> nb   (nb's tile t-1 reads done by (t-1).P2-end barrier)
//   t.P3: stage Ah0,Bh0(t+2) -> cur  (cur's tile t reads done by t.P2-end barrier)
//   t.P3-end ledger (2 loads/STAGE): [Ah0Bh0(t+1)]4 + [Ah1Bh1(t+1)]4 + [Ah0Bh0(t+2)]4 = 12
//     -> s_waitcnt vmcnt(4): oldest 8 done = ALL of t+1 staged; 4 stay in flight (no drain).
// Min stage->wait slack = 3 phases (covers ~900cy HBM latency); R1 had 1 phase.
// Tail stages clamp the tile index (redundant loads, never read) so per-wave vmcnt
// accounting stays exact; vmcnt(0) drains before exit (stray LDS writes would corrupt
// the next block's LDS otherwise).
// LDS swizzle: row r stores global granule g at granule g^(r&7) (pre-swizzled global
// address; global_load_lds dest stays linear). Fragment ds_read_b128 is conflict-free.
#define BM  256
#define BN  256
#define BKT 64
#define HTILE 8192   // shorts per half-tile: 128 rows x 64

template <int MODE, int M, int N, int K>
__global__ __launch_bounds__(512, 2) void gemm_kernel(
    const unsigned short* __restrict__ Aall,   // per-expert M x K (bf16, K-contig)
    const unsigned short* __restrict__ Ball,   // per-expert N x K (bf16, K-contig)
    const float* __restrict__ biasAll,         // per-expert N
    unsigned short* __restrict__ Hall,         // MODE 1
    float* __restrict__ Out,                   // MODE 2
    const int* __restrict__ sel, const float* __restrict__ selw) {

  __shared__ __align__(16) unsigned short As[2 * 2 * HTILE];  // [buf][m_w half][128*64]
  __shared__ __align__(16) unsigned short Bs[2 * 2 * HTILE];  // [buf][hb half][128*64]
  __shared__ int   selS[BM];
  __shared__ float wS[BM];

  int tid = threadIdx.x, lane = tid & 63, wave = tid >> 6;
  int m_w = wave >> 2, n_w = wave & 3;         // 2 waves in M x 4 waves in N
  int hb  = n_w >> 1, nb0 = (n_w & 1) * 64;    // wave's B half + offset inside it
  int row = lane & 15, quad = lane >> 4, r7 = row & 7;
  int r8 = lane >> 3, j8 = lane & 7;           // staging lane decomposition

  // block decode with bijective XCD swizzle (nwg % 8 == 0 for both GEMMs)
  constexpr int nxt = N >> 8, nyt = M >> 8, per = nxt * nyt;
  constexpr int nwg = per * NEXP;
  int bid = blockIdx.x;
  int swz = (bid & 7) * (nwg >> 3) + (bid >> 3);
  int e   = swz / per;
  int rem = swz - e * per;
  int by  = rem / nxt;
  int bx  = rem - by * nxt;
  int m0 = by * BM, n0 = bx * BN;
  constexpr int NT = K / BKT;

  const unsigned short* A = Aall + (size_t)e * M * K;
  const unsigned short* B = Ball + (size_t)e * N * K;
  const float* bias = biasAll + (size_t)e * N;

  if (MODE == 2 && tid < BM) {
    selS[tid] = sel[e * KCAP + m0 + tid];
    wS[tid]   = selw[e * KCAP + m0 + tid];
  }
  __syncthreads();   // before any prefetch is issued, so the drain costs nothing

// stage one half-tile: rows [RC0 + HALF*128 + wave*16, +16), global col pre-swizzled
#define STAGE(DST, G, RC0, TT, HALF, BUF)                                              \
  do {                                                                                 \
    int tt_ = (TT) < NT ? (TT) : NT - 1;                                               \
    const unsigned short* g_ =                                                         \
        (G) + (size_t)((RC0) + (HALF) * 128 + wave * 16 + r8) * K + tt_ * BKT +        \
        ((j8 ^ r8) << 3);                                                              \
    unsigned short* l_ = (DST) + ((BUF) * 2 + (HALF)) * HTILE + wave * 16 * 64;        \
    __builtin_amdgcn_global_load_lds((const __attribute__((address_space(1))) void*)g_,\
        (__attribute__((address_space(3))) void*)l_, 16, 0, 0);                        \
    __builtin_amdgcn_global_load_lds(                                                  \
        (const __attribute__((address_space(1))) void*)(g_ + (size_t)8 * K),           \
        (__attribute__((address_space(3))) void*)(l_ + 8 * 64), 16, 0, 0);             \
  } while (0)

// fragment loads (ds_read_b128) out of the swizzled layout
#define LDA(MQ)                                                                        \
  _Pragma("unroll") for (int ti = 0; ti < 4; ++ti)                                     \
  _Pragma("unroll") for (int kki = 0; kki < 2; ++kki)                                  \
    a[ti][kki] = *(const shortx8*)&As[(cur * 2 + m_w) * HTILE +                        \
        ((MQ) * 64 + ti * 16 + row) * 64 + (((quad + 4 * kki) ^ r7) << 3)];

#define LDB(BREG, NQ)                                                                  \
  _Pragma("unroll") for (int tj = 0; tj < 2; ++tj)                                     \
  _Pragma("unroll") for (int kki = 0; kki < 2; ++kki)                                  \
    BREG[tj][kki] = *(const shortx8*)&Bs[(cur * 2 + hb) * HTILE +                      \
        (nb0 + (NQ) * 32 + tj * 16 + row) * 64 + (((quad + 4 * kki) ^ r7) << 3)];

// kki OUTER: consecutive MFMAs hit different accumulators (no same-acc back-to-back)
#define MFMAQ(MQ, BREG, NQ)                                                            \
  _Pragma("unroll") for (int kki = 0; kki < 2; ++kki)                                  \
  _Pragma("unroll") for (int ti = 0; ti < 4; ++ti)                                     \
  _Pragma("unroll") for (int tj = 0; tj < 2; ++tj)                                     \
    acc[(MQ) * 4 + ti][(NQ) * 2 + tj] = __builtin_amdgcn_mfma_f32_16x16x32_bf16(       \
        a[ti][kki], BREG[tj][kki], acc[(MQ) * 4 + ti][(NQ) * 2 + tj], 0, 0, 0);

#define PH_MID()                                                                       \
  __builtin_amdgcn_s_barrier();                                                        \
  asm volatile("s_waitcnt lgkmcnt(0)" ::: "memory");                                   \
  __builtin_amdgcn_s_setprio(1);

#define PH_END()                                                                       \
  __builtin_amdgcn_s_setprio(0);                                                       \
  __builtin_amdgcn_s_barrier();

#define PH_END_VM(NN)                                                                  \
  __builtin_amdgcn_s_setprio(0);                                                       \
  asm volatile("s_waitcnt vmcnt(" #NN ")" ::: "memory");                               \
  __builtin_amdgcn_s_barrier();

  floatx4 acc[8][4];
  floatx4 zero = {0.f, 0.f, 0.f, 0.f};
#pragma unroll
  for (int i = 0; i < 8; ++i)
#pragma unroll
    for (int j = 0; j < 4; ++j) acc[i][j] = zero;

  shortx8 a[4][2], b0[2][2], b1[2][2];

  // prologue: tile0 all four halves + tile1 Ah0,Bh0; vmcnt(4) = tile0 fully staged,
  // [Ah0Bh0(1)] left in flight — matches the steady-state loop-entry invariant.
  STAGE(As, A, m0, 0, 0, 0);
  STAGE(Bs, B, n0, 0, 0, 0);
  STAGE(As, A, m0, 0, 1, 0);
  STAGE(Bs, B, n0, 0, 1, 0);
  STAGE(As, A, m0, 1, 0, 1);
  STAGE(Bs, B, n0, 1, 0, 1);
  asm volatile("s_waitcnt vmcnt(4)" ::: "memory");
  __builtin_amdgcn_s_barrier();

  for (int t = 0; t < NT; ++t) {
    int cur = t & 1, nb = cur ^ 1;
    // P0: quadrant (m0,n0); 12 ds_reads; stage Ah1,Bh1(t+1)
    LDA(0); LDB(b0, 0);
    STAGE(As, A, m0, t + 1, 1, nb);
    STAGE(Bs, B, n0, t + 1, 1, nb);
    asm volatile("s_waitcnt lgkmcnt(8)" ::: "memory");
    PH_MID(); MFMAQ(0, b0, 0); PH_END();
    // P1: quadrant (m0,n1); 4 ds_reads
    LDB(b1, 1);
    PH_MID(); MFMAQ(0, b1, 1); PH_END();
    // P2: quadrant (m1,n0); 8 ds_reads
    LDA(1);
    PH_MID(); MFMAQ(1, b0, 0); PH_END();
    // P3: quadrant (m1,n1); stage Ah0,Bh0(t+2) into cur (cur's reads done at P2-end);
    //     vmcnt(4) -> all of t+1 staged, t+2's first two halves stay in flight
    STAGE(As, A, m0, t + 2, 0, cur);
    STAGE(Bs, B, n0, t + 2, 0, cur);
    PH_MID(); MFMAQ(1, b1, 1); PH_END_VM(4);
  }
  asm volatile("s_waitcnt vmcnt(0)" ::: "memory");  // drain tail stages before exit

  // epilogue: C/D layout col=lane&15, row=quad*4+reg  [m89/m91-verified]
#pragma unroll
  for (int ti = 0; ti < 8; ++ti) {
#pragma unroll
    for (int tj = 0; tj < 4; ++tj) {
      int gn = n0 + n_w * 64 + tj * 16 + row;
      float bb = bias[gn];
#pragma unroll
      for (int r = 0; r < 4; ++r) {
        int lrow = m_w * 128 + ti * 16 + quad * 4 + r;
        float v = acc[ti][tj][r] + bb;
        if (MODE == 1) {
          float u = 0.7978845608028654f * (v + 0.044715f * v * v * v);
          u = fminf(u, 15.f);                       // overflow guard; tanh(15)==1
          float e2 = __expf(2.f * u);
          float th = __fdividef(e2 - 1.f, e2 + 1.f);
          float g = 0.5f * v * (1.f + th);
          Hall[(size_t)e * M * N + (size_t)(m0 + lrow) * N + gn] = f2bf(g);
        } else {
          atomicAdd(&Out[(size_t)selS[lrow] * DIM + gn], wS[lrow] * v);
        }
      }
    }
  }
#undef STAGE
#undef LDA
#undef LDB
#undef MFMAQ
#undef PH_MID
#undef PH_END
#undef PH_END_VM
}

extern "C" void kernel_launch(void* const* d_in, const int* in_sizes, int n_in,
                              void* d_out, int out_size, void* d_ws, size_t ws_size,
                              hipStream_t stream) {
  const float* x   = (const float*)d_in[0];
  const float* gw  = (const float*)d_in[1];
  const float* lnw = (const float*)d_in[2];
  const float* lnb = (const float*)d_in[3];
  const float* fc1 = (const float*)d_in[4];
  const float* b1  = (const float*)d_in[5];
  const float* fc2 = (const float*)d_in[6];
  const float* b2  = (const float*)d_in[7];
  float* out = (float*)d_out;

  char* p = (char*)d_ws;
  float* scores = (float*)p;                 p += (size_t)NEXP * TOK * 4;     // 512 KB
  int*   sel    = (int*)p;                   p += (size_t)NEXP * KCAP * 4;    // 64 KB
  float* selw   = (float*)p;                 p += (size_t)NEXP * KCAP * 4;    // 64 KB
  unsigned short* Wb = (unsigned short*)p;   p += (size_t)NEXP * DDIM * DIM * 2; // 64 MB (fc1 then fc2)
  unsigned short* Y  = (unsigned short*)p;   p += (size_t)NEXP * KCAP * DIM * 2; // 32 MB
  unsigned short* H  = (unsigned short*)p;   p += (size_t)NEXP * KCAP * DDIM * 2; // 128 MB

  // out = x (scatter-add base)
  hipMemcpyAsync(out, x, (size_t)TOK * DIM * sizeof(float), hipMemcpyDeviceToDevice, stream);

  // gating + selection + LN gather
  gate_kernel<<<TOK / 4, 256, 0, stream>>>(x, gw, scores);
  topk_kernel<<<NEXP, TKT, 0, stream>>>(scores, sel, selw);
  gather_ln_kernel<<<dim3(KCAP, NEXP), 256, 0, stream>>>(x, sel, lnw, lnb, Y);

  // GEMM1: H = gelu(Y @ fc1^T + b1)
  const int n4w = NEXP * DDIM * DIM / 4;
  cvt_kernel<<<n4w / 256, 256, 0, stream>>>(fc1, Wb, n4w);
  gemm_kernel<1, KCAP, DDIM, DIM><<<dim3((DDIM / BN) * (KCAP / BM) * NEXP), 512, 0, stream>>>(
      Y, Wb, b1, H, nullptr, nullptr, nullptr);

  // GEMM2: out[sel] += selw * (H @ fc2^T + b2)   (Wb reused for fc2)
  cvt_kernel<<<n4w / 256, 256, 0, stream>>>(fc2, Wb, n4w);
  gemm_kernel<2, KCAP, DIM, DDIM><<<dim3((DIM / BN) * (KCAP / BM) * NEXP), 512, 0, stream>>>(
      H, Wb, b2, nullptr, out, sel, selw);
}

// Round 5
// 767.172 us; speedup vs baseline: 1.0777x; 1.0777x over previous
//
#include <hip/hip_runtime.h>

#define TOK  16384
#define NEXP 8
#define DIM  1024
#define DDIM 4096
#define KCAP 2048

typedef float  floatx4 __attribute__((ext_vector_type(4)));
typedef short  shortx8 __attribute__((ext_vector_type(8)));

static __device__ __forceinline__ unsigned short f2bf(float x) {
  unsigned u = __float_as_uint(x);
  return (unsigned short)((u + 0x7fffu + ((u >> 16) & 1u)) >> 16);
}

// ---------------- fp32 -> bf16 weight convert ----------------
__global__ __launch_bounds__(256) void cvt_kernel(const float* __restrict__ src,
                                                  unsigned short* __restrict__ dst, int n4) {
  int i = blockIdx.x * 256 + threadIdx.x;
  if (i < n4) {
    float4 v = ((const float4*)src)[i];
    ushort4 o = make_ushort4(f2bf(v.x), f2bf(v.y), f2bf(v.z), f2bf(v.w));
    ((ushort4*)dst)[i] = o;
  }
}

// ---------------- gating: logits + softmax; also writes out = x (replaces memcpy) ----
__global__ __launch_bounds__(256) void gate_kernel(const float* __restrict__ x,
                                                   const float* __restrict__ gw,
                                                   float* __restrict__ scores,
                                                   float* __restrict__ out) {
  __shared__ float gws[NEXP * DIM];
  int tid = threadIdx.x;
  for (int i = tid; i < NEXP * DIM / 4; i += 256)
    ((float4*)gws)[i] = ((const float4*)gw)[i];
  __syncthreads();
  int wave = tid >> 6, lane = tid & 63;
  int t = blockIdx.x * 4 + wave;
  const float4* xr = (const float4*)(x + (size_t)t * DIM);
  float4 xv[4];
#pragma unroll
  for (int j = 0; j < 4; ++j) xv[j] = xr[j * 64 + lane];
  // out = x (scatter-add base) — fused here since we already hold the row
  float4* orow = (float4*)(out + (size_t)t * DIM);
#pragma unroll
  for (int j = 0; j < 4; ++j) orow[j * 64 + lane] = xv[j];
  float acc[NEXP];
#pragma unroll
  for (int e = 0; e < NEXP; ++e) acc[e] = 0.f;
#pragma unroll
  for (int e = 0; e < NEXP; ++e) {
    const float4* g4 = (const float4*)(gws + e * DIM);
#pragma unroll
    for (int j = 0; j < 4; ++j) {
      float4 g = g4[j * 64 + lane];
      acc[e] += xv[j].x * g.x + xv[j].y * g.y + xv[j].z * g.z + xv[j].w * g.w;
    }
  }
#pragma unroll
  for (int off = 32; off > 0; off >>= 1) {
#pragma unroll
    for (int e = 0; e < NEXP; ++e) acc[e] += __shfl_down(acc[e], off);
  }
  if (lane == 0) {
    float mx = acc[0];
#pragma unroll
    for (int e = 1; e < NEXP; ++e) mx = fmaxf(mx, acc[e]);
    float ex[NEXP], sum = 0.f;
#pragma unroll
    for (int e = 0; e < NEXP; ++e) { ex[e] = expf(acc[e] - mx); sum += ex[e]; }
    float inv = 1.f / sum;
#pragma unroll
    for (int e = 0; e < NEXP; ++e) scores[(size_t)e * TOK + t] = ex[e] * inv;
  }
}

// ---------------- per-expert exact top-k via 3-level histogram radix select ----------
// (verified in R3) Levels: bits [31:21], [20:10], [9:0]. T = exact k-th-largest bits,
// n_gt = count(v > T). Selection pass (lowest-index tie-break) identical to the
// original radix-search version.
#define TKT 1024
#define TKW (TKT / 64)

__device__ __forceinline__ void walk_suffix(const int* hist, int nbins, int cnt_in,
                                            int tid, int* shOut) {
  if (tid < 64) {
    int lane = tid;
    int cum = 0;
    for (int g = nbins / 64 - 1; g >= 0; --g) {
      int c = hist[g * 64 + lane];
      int s = c;
#pragma unroll
      for (int off = 1; off < 64; off <<= 1) {
        int o = __shfl_down(s, off);
        if (lane + off < 64) s += o;
      }
      int gs = __shfl(s, 0);
      if (cnt_in + cum + gs >= KCAP) {
        unsigned long long m = __ballot(cnt_in + cum + s >= KCAP);
        int l = 63 - __clzll(m);
        int sAt = __shfl(s, l), cAt = __shfl(c, l);
        if (lane == 0) { shOut[0] = g * 64 + l; shOut[1] = cnt_in + cum + sAt - cAt; }
        break;
      }
      cum += gs;
    }
  }
}

__global__ __launch_bounds__(TKT) void topk_kernel(const float* __restrict__ scores,
                                                   int* __restrict__ sel,
                                                   float* __restrict__ selw) {
  int e = blockIdx.x;
  const float* s = scores + (size_t)e * TOK;
  int tid = threadIdx.x, lane = tid & 63, wave = tid >> 6;
  __shared__ int hist[2048];
  __shared__ int shBin[2];
  __shared__ int wsum[TKW];

  // level 1: bits [31:21]
  for (int i = tid; i < 2048; i += TKT) hist[i] = 0;
  __syncthreads();
  for (int i = tid; i < TOK; i += TKT)
    atomicAdd(&hist[__float_as_uint(s[i]) >> 21], 1);
  __syncthreads();
  walk_suffix(hist, 2048, 0, tid, shBin);
  __syncthreads();
  unsigned bin1 = (unsigned)shBin[0];
  int cab = shBin[1];
  __syncthreads();

  // level 2: bits [20:10] within bin1
  for (int i = tid; i < 2048; i += TKT) hist[i] = 0;
  __syncthreads();
  for (int i = tid; i < TOK; i += TKT) {
    unsigned v = __float_as_uint(s[i]);
    if ((v >> 21) == bin1) atomicAdd(&hist[(v >> 10) & 0x7FFu], 1);
  }
  __syncthreads();
  walk_suffix(hist, 2048, cab, tid, shBin);
  __syncthreads();
  unsigned pre21 = (bin1 << 11) | (unsigned)shBin[0];
  cab = shBin[1];
  __syncthreads();

  // level 3: bits [9:0] within pre21
  for (int i = tid; i < 1024; i += TKT) hist[i] = 0;
  __syncthreads();
  for (int i = tid; i < TOK; i += TKT) {
    unsigned v = __float_as_uint(s[i]);
    if ((v >> 10) == pre21) atomicAdd(&hist[v & 0x3FFu], 1);
  }
  __syncthreads();
  walk_suffix(hist, 1024, cab, tid, shBin);
  __syncthreads();
  unsigned T = (pre21 << 10) | (unsigned)shBin[0];
  int n_gt = shBin[1];
  int need = KCAP - n_gt;

  __shared__ int pos;
  __shared__ int tiebase;
  if (tid == 0) { pos = 0; tiebase = 0; }
  __syncthreads();
  for (int chunk = 0; chunk < TOK; chunk += TKT) {
    int i = chunk + tid;
    unsigned v = __float_as_uint(s[i]);
    if (v > T) {
      int p = atomicAdd(&pos, 1);
      sel[e * KCAP + p]  = i;
      selw[e * KCAP + p] = __uint_as_float(v);
    }
    bool tie = (v == T);
    unsigned long long m = __ballot(tie);
    if (lane == 0) wsum[wave] = __popcll(m);
    __syncthreads();
    int base = tiebase;
    for (int w = 0; w < wave; ++w) base += wsum[w];
    int rank = base + __popcll(m & ((1ull << lane) - 1ull));
    if (tie && rank < need) {
      sel[e * KCAP + n_gt + rank]  = i;
      selw[e * KCAP + n_gt + rank] = __uint_as_float(T);
    }
    __syncthreads();
    if (tid == 0) {
      int tb = 0;
#pragma unroll
      for (int w = 0; w < TKW; ++w) tb += wsum[w];
      tiebase += tb;
    }
    __syncthreads();
  }
}

// ---------------- gather selected tokens + layernorm -> bf16 Y ----------------
__global__ __launch_bounds__(256) void gather_ln_kernel(const float* __restrict__ x,
                                                        const int* __restrict__ sel,
                                                        const float* __restrict__ lnw,
                                                        const float* __restrict__ lnb,
                                                        unsigned short* __restrict__ Y) {
  int e = blockIdx.y, i = blockIdx.x;
  int tid = threadIdx.x, lane = tid & 63, wave = tid >> 6;
  int t = sel[e * KCAP + i];
  const float4* xr = (const float4*)(x + (size_t)t * DIM);
  float4 v = xr[tid];
  float s  = v.x + v.y + v.z + v.w;
  float sq = v.x * v.x + v.y * v.y + v.z * v.z + v.w * v.w;
#pragma unroll
  for (int off = 32; off > 0; off >>= 1) { s += __shfl_down(s, off); sq += __shfl_down(sq, off); }
  __shared__ float red[8];
  if (lane == 0) { red[wave] = s; red[4 + wave] = sq; }
  __syncthreads();
  s  = red[0] + red[1] + red[2] + red[3];
  sq = red[4] + red[5] + red[6] + red[7];
  float mu  = s * (1.f / DIM);
  float var = sq * (1.f / DIM) - mu * mu;
  float rs  = rsqrtf(var + 1e-5f);
  float4 w = ((const float4*)lnw)[tid];
  float4 b = ((const float4*)lnb)[tid];
  ushort4 o = make_ushort4(f2bf((v.x - mu) * rs * w.x + b.x),
                           f2bf((v.y - mu) * rs * w.y + b.y),
                           f2bf((v.z - mu) * rs * w.z + b.z),
                           f2bf((v.w - mu) * rs * w.w + b.w));
  ((ushort4*)(Y + ((size_t)e * KCAP + i) * DIM))[tid] = o;
}

// ---------------- bf16 MFMA GEMM: 256x256 tile, BK=64, 8-wave 8-phase pipeline ----------
// EXACT R1 schedule (best measured: 206 us/dispatch). 2 K-tile LDS double buffer split in
// 4 half-tiles; one half-tile staged per phase:
//   tile t: P0->(t+1,Ah1)  P1->(t+1,Bh0)  P2->(t+1,Bh1)  P3->(t+2,Ah0)
// At P3: s_waitcnt vmcnt(2) leaves only (t+2,Ah0) in flight => tile t+1 fully staged,
// prefetch never drained. Each stage's LDS target was consumed >=2 barriers earlier.
// Tail stages clamp the K offset (redundant, never-read loads) so per-wave vmcnt
// accounting stays exact; trailing vmcnt(0) drains before the epilogue (stray LDS
// writes after endpgm would corrupt the next block's LDS).
// Runtime M,N,K on purpose: constexpr NT invites full K-loop unroll -> I-cache thrash
// (suspected cause of the R3 10% regression).
#define BM  256
#define BN  256
#define BKT 64
#define HTILE 8192   // shorts per half-tile: 128 rows x 64

template <int MODE>
__global__ __launch_bounds__(512, 2) void gemm_kernel(
    const unsigned short* __restrict__ Aall,   // per-expert M x K (bf16, K-contig)
    const unsigned short* __restrict__ Ball,   // per-expert N x K (bf16, K-contig)
    const float* __restrict__ biasAll,         // per-expert N
    int M, int N, int K,
    unsigned short* __restrict__ Hall,         // MODE 1
    float* __restrict__ Out,                   // MODE 2
    const int* __restrict__ sel, const float* __restrict__ selw) {

  __shared__ __align__(16) unsigned short As[2 * 2 * HTILE];  // [buf][half][128*64]
  __shared__ __align__(16) unsigned short Bs[2 * 2 * HTILE];
  __shared__ int   selS[BM];
  __shared__ float wS[BM];

  int tid = threadIdx.x, lane = tid & 63, wave = tid >> 6;
  int m_w = wave >> 2, n_w = wave & 3;         // 2 waves in M x 4 waves in N
  int hb  = n_w >> 1, nb0 = (n_w & 1) * 64;    // wave's B half + offset inside it
  int row = lane & 15, quad = lane >> 4, r7 = row & 7;
  int r8 = lane >> 3, j8 = lane & 7;           // staging lane decomposition

  // block decode with bijective XCD swizzle (nwg % 8 == 0 for both GEMMs)
  int nxt = N >> 8, nyt = M >> 8, per = nxt * nyt;
  int nwg = per * NEXP;
  int bid = blockIdx.x;
  int swz = (bid & 7) * (nwg >> 3) + (bid >> 3);
  int e   = swz / per;
  int rem = swz - e * per;
  int by  = rem / nxt;
  int bx  = rem - by * nxt;
  int m0 = by * BM, n0 = bx * BN;
  int NT = K / BKT;

  const unsigned short* A = Aall + (size_t)e * M * K;
  const unsigned short* B = Ball + (size_t)e * N * K;
  const float* bias = biasAll + (size_t)e * N;

  if (MODE == 2 && tid < BM) {
    selS[tid] = sel[e * KCAP + m0 + tid];
    wS[tid]   = selw[e * KCAP + m0 + tid];
  }
  __syncthreads();   // before any prefetch is issued, so the drain costs nothing

// stage one half-tile: rows [RC0 + HALF*128 + wave*16, +16), global col pre-swizzled
#define STAGE(DST, G, RC0, TT, HALF, BUF)                                              \
  do {                                                                                 \
    int tt_ = (TT) < NT ? (TT) : NT - 1;                                               \
    const unsigned short* g_ =                                                         \
        (G) + (size_t)((RC0) + (HALF) * 128 + wave * 16 + r8) * K + tt_ * BKT +        \
        ((j8 ^ r8) << 3);                                                              \
    unsigned short* l_ = (DST) + ((BUF) * 2 + (HALF)) * HTILE + wave * 16 * 64;        \
    __builtin_amdgcn_global_load_lds((const __attribute__((address_space(1))) void*)g_,\
        (__attribute__((address_space(3))) void*)l_, 16, 0, 0);                        \
    __builtin_amdgcn_global_load_lds(                                                  \
        (const __attribute__((address_space(1))) void*)(g_ + (size_t)8 * K),           \
        (__attribute__((address_space(3))) void*)(l_ + 8 * 64), 16, 0, 0);             \
  } while (0)

// fragment loads (ds_read_b128) out of the swizzled layout
#define LDA(MQ)                                                                        \
  _Pragma("unroll") for (int ti = 0; ti < 4; ++ti)                                     \
  _Pragma("unroll") for (int kki = 0; kki < 2; ++kki)                                  \
    a[ti][kki] = *(const shortx8*)&As[(cur * 2 + m_w) * HTILE +                        \
        ((MQ) * 64 + ti * 16 + row) * 64 + (((quad + 4 * kki) ^ r7) << 3)];

#define LDB(BREG, NQ)                                                                  \
  _Pragma("unroll") for (int tj = 0; tj < 2; ++tj)                                     \
  _Pragma("unroll") for (int kki = 0; kki < 2; ++kki)                                  \
    BREG[tj][kki] = *(const shortx8*)&Bs[(cur * 2 + hb) * HTILE +                      \
        (nb0 + (NQ) * 32 + tj * 16 + row) * 64 + (((quad + 4 * kki) ^ r7) << 3)];

#define MFMAQ(MQ, BREG, NQ)                                                            \
  _Pragma("unroll") for (int ti = 0; ti < 4; ++ti)                                     \
  _Pragma("unroll") for (int tj = 0; tj < 2; ++tj)                                     \
  _Pragma("unroll") for (int kki = 0; kki < 2; ++kki)                                  \
    acc[(MQ) * 4 + ti][(NQ) * 2 + tj] = __builtin_amdgcn_mfma_f32_16x16x32_bf16(       \
        a[ti][kki], BREG[tj][kki], acc[(MQ) * 4 + ti][(NQ) * 2 + tj], 0, 0, 0);

#define PH_MID()                                                                       \
  __builtin_amdgcn_s_barrier();                                                        \
  asm volatile("s_waitcnt lgkmcnt(0)" ::: "memory");                                   \
  __builtin_amdgcn_s_setprio(1);

#define PH_END()                                                                       \
  __builtin_amdgcn_s_setprio(0);                                                       \
  __builtin_amdgcn_s_barrier();

#define PH_END_VM()                                                                    \
  __builtin_amdgcn_s_setprio(0);                                                       \
  asm volatile("s_waitcnt vmcnt(2)" ::: "memory");                                     \
  __builtin_amdgcn_s_barrier();

  floatx4 acc[8][4];
  floatx4 zero = {0.f, 0.f, 0.f, 0.f};
#pragma unroll
  for (int i = 0; i < 8; ++i)
#pragma unroll
    for (int j = 0; j < 4; ++j) acc[i][j] = zero;

  shortx8 a[4][2], b0[2][2], b1[2][2];

  // prologue: tile0 all 4 halves + tile1 Ah0; wait tile0 (8 oldest of 10) done
  STAGE(As, A, m0, 0, 0, 0);
  STAGE(As, A, m0, 0, 1, 0);
  STAGE(Bs, B, n0, 0, 0, 0);
  STAGE(Bs, B, n0, 0, 1, 0);
  STAGE(As, A, m0, 1, 0, 1);
  asm volatile("s_waitcnt vmcnt(2)" ::: "memory");
  __builtin_amdgcn_s_barrier();

  for (int t = 0; t < NT; ++t) {
    int cur = t & 1, nb = cur ^ 1;
    // P0: quadrant (m0,n0); 12 ds_reads
    LDA(0); LDB(b0, 0);
    STAGE(As, A, m0, t + 1, 1, nb);
    asm volatile("s_waitcnt lgkmcnt(8)" ::: "memory");
    PH_MID(); MFMAQ(0, b0, 0); PH_END();
    // P1: quadrant (m0,n1); 4 ds_reads
    LDB(b1, 1);
    STAGE(Bs, B, n0, t + 1, 0, nb);
    PH_MID(); MFMAQ(0, b1, 1); PH_END();
    // P2: quadrant (m1,n0); 8 ds_reads
    LDA(1);
    STAGE(Bs, B, n0, t + 1, 1, nb);
    PH_MID(); MFMAQ(1, b0, 0); PH_END();
    // P3: quadrant (m1,n1); counted vmcnt — only (t+2,Ah0) may stay in flight
    STAGE(As, A, m0, t + 2, 0, cur);
    PH_MID(); MFMAQ(1, b1, 1); PH_END_VM();
  }
  asm volatile("s_waitcnt vmcnt(0)" ::: "memory");  // drain tail stages before exit

  // epilogue: C/D layout col=lane&15, row=quad*4+reg  [m89/m91-verified]
#pragma unroll
  for (int ti = 0; ti < 8; ++ti) {
#pragma unroll
    for (int tj = 0; tj < 4; ++tj) {
      int gn = n0 + n_w * 64 + tj * 16 + row;
      float bb = bias[gn];
#pragma unroll
      for (int r = 0; r < 4; ++r) {
        int lrow = m_w * 128 + ti * 16 + quad * 4 + r;
        float v = acc[ti][tj][r] + bb;
        if (MODE == 1) {
          float u = 0.7978845608028654f * (v + 0.044715f * v * v * v);
          u = fminf(u, 15.f);                       // overflow guard; tanh(15)==1
          float e2 = __expf(2.f * u);
          float th = __fdividef(e2 - 1.f, e2 + 1.f);
          float g = 0.5f * v * (1.f + th);
          Hall[(size_t)e * M * N + (size_t)(m0 + lrow) * N + gn] = f2bf(g);
        } else {
          atomicAdd(&Out[(size_t)selS[lrow] * DIM + gn], wS[lrow] * v);
        }
      }
    }
  }
#undef STAGE
#undef LDA
#undef LDB
#undef MFMAQ
#undef PH_MID
#undef PH_END
#undef PH_END_VM
}

extern "C" void kernel_launch(void* const* d_in, const int* in_sizes, int n_in,
                              void* d_out, int out_size, void* d_ws, size_t ws_size,
                              hipStream_t stream) {
  const float* x   = (const float*)d_in[0];
  const float* gw  = (const float*)d_in[1];
  const float* lnw = (const float*)d_in[2];
  const float* lnb = (const float*)d_in[3];
  const float* fc1 = (const float*)d_in[4];
  const float* b1  = (const float*)d_in[5];
  const float* fc2 = (const float*)d_in[6];
  const float* b2  = (const float*)d_in[7];
  float* out = (float*)d_out;

  char* p = (char*)d_ws;
  float* scores = (float*)p;                 p += (size_t)NEXP * TOK * 4;     // 512 KB
  int*   sel    = (int*)p;                   p += (size_t)NEXP * KCAP * 4;    // 64 KB
  float* selw   = (float*)p;                 p += (size_t)NEXP * KCAP * 4;    // 64 KB
  unsigned short* Wb = (unsigned short*)p;   p += (size_t)NEXP * DDIM * DIM * 2; // 64 MB (fc1 then fc2)
  unsigned short* Y  = (unsigned short*)p;   p += (size_t)NEXP * KCAP * DIM * 2; // 32 MB
  unsigned short* H  = (unsigned short*)p;   p += (size_t)NEXP * KCAP * DDIM * 2; // 128 MB

  // gating (also writes out = x) + selection + LN gather
  gate_kernel<<<TOK / 4, 256, 0, stream>>>(x, gw, scores, out);
  topk_kernel<<<NEXP, TKT, 0, stream>>>(scores, sel, selw);
  gather_ln_kernel<<<dim3(KCAP, NEXP), 256, 0, stream>>>(x, sel, lnw, lnb, Y);

  // GEMM1: H = gelu(Y @ fc1^T + b1)
  const int n4w = NEXP * DDIM * DIM / 4;
  cvt_kernel<<<n4w / 256, 256, 0, stream>>>(fc1, Wb, n4w);
  gemm_kernel<1><<<dim3((DDIM / BN) * (KCAP / BM) * NEXP), 512, 0, stream>>>(
      Y, Wb, b1, KCAP, DDIM, DIM, H, nullptr, nullptr, nullptr);

  // GEMM2: out[sel] += selw * (H @ fc2^T + b2)   (Wb reused for fc2)
  cvt_kernel<<<n4w / 256, 256, 0, stream>>>(fc2, Wb, n4w);
  gemm_kernel<2><<<dim3((DIM / BN) * (KCAP / BM) * NEXP), 512, 0, stream>>>(
      H, Wb, b2, KCAP, DIM, DDIM, nullptr, out, sel, selw);
}